// Round 7
// baseline (706.392 us; speedup 1.0000x reference)
//
#include <hip/hip_runtime.h>
#include <hip/hip_bf16.h>
#include <math.h>

#define N_NODES 100000
#define N_EDGES 1600000
#define F_IN 512
#define HID 128
#define NCLS 40

typedef __attribute__((ext_vector_type(8))) short short8;
typedef __attribute__((ext_vector_type(4))) float floatx4;

__device__ __forceinline__ unsigned short f2bf(float x) {
    unsigned u = __builtin_bit_cast(unsigned, x);
    unsigned r = (u + 0x7FFFu + ((u >> 16) & 1u)) >> 16;   // RNE
    return (unsigned short)r;
}
__device__ __forceinline__ float bflo(unsigned u) {
    return __builtin_bit_cast(float, u << 16);
}
__device__ __forceinline__ float bfhi(unsigned u) {
    return __builtin_bit_cast(float, u & 0xFFFF0000u);
}
__device__ __forceinline__ unsigned pk2bf(float a, float b) {
    // v_cvt_pk_bf16_f32 on gfx950 (RNE), packs (a->lo, b->hi)
    __hip_bfloat162 h = __float22bfloat162_rn(make_float2(a, b));
    return *(unsigned*)&h;
}

// ---------------- utility ----------------

__global__ void k_zero_int(int* p, int n) {
    int i = blockIdx.x * blockDim.x + threadIdx.x;
    if (i < n) p[i] = 0;
}

// ---------------- degree ----------------

__global__ void k_count_deg(const int* __restrict__ dst, int* __restrict__ deg, int e) {
    int i = blockIdx.x * blockDim.x + threadIdx.x;
    if (i < e) atomicAdd(&deg[dst[i]], 1);
}

// ---------------- exclusive scan (3-kernel), inv fused into scan1 ------------

#define SCAN_B 256

__global__ __launch_bounds__(SCAN_B) void k_scan1(const int* __restrict__ deg,
                                                  int* __restrict__ rp,
                                                  int* __restrict__ bsums,
                                                  float* __restrict__ inv, int n) {
    __shared__ int s[SCAN_B];
    int tid = threadIdx.x;
    int i = blockIdx.x * SCAN_B + tid;
    int v = (i < n) ? deg[i] : 0;
    if (i < n) inv[i] = rsqrtf((float)v + 1.0f);   // +1 self loop
    s[tid] = v;
    __syncthreads();
    for (int off = 1; off < SCAN_B; off <<= 1) {
        int t = (tid >= off) ? s[tid - off] : 0;
        __syncthreads();
        s[tid] += t;
        __syncthreads();
    }
    if (i < n) rp[i] = s[tid] - v;                 // exclusive
    if (tid == SCAN_B - 1) bsums[blockIdx.x] = s[tid];
}

__global__ __launch_bounds__(512) void k_scan2(int* __restrict__ bsums, int nb) {
    __shared__ int s[512];
    int tid = threadIdx.x;
    int v = (tid < nb) ? bsums[tid] : 0;
    s[tid] = v;
    __syncthreads();
    for (int off = 1; off < 512; off <<= 1) {
        int t = (tid >= off) ? s[tid - off] : 0;
        __syncthreads();
        s[tid] += t;
        __syncthreads();
    }
    if (tid < nb) bsums[tid] = s[tid] - v;         // exclusive block offsets
}

__global__ void k_scan3(int* __restrict__ rp, const int* __restrict__ bsums,
                        int* __restrict__ cursor, int n) {
    int i = blockIdx.x * SCAN_B + threadIdx.x;
    if (i < n) {
        int v = rp[i] + bsums[blockIdx.x];
        rp[i] = v;
        cursor[i] = v;     // fill-cursor starts at row pointer
    }
}

// ---------------- CSR fill (counting sort by dst) ----------------

__global__ void k_fill(const int* __restrict__ src, const int* __restrict__ dst,
                       int* __restrict__ cursor, int* __restrict__ csr_src, int e) {
    int i = blockIdx.x * blockDim.x + threadIdx.x;
    if (i >= e) return;
    int d = dst[i];
    int pos = atomicAdd(&cursor[d], 1);
    csr_src[pos] = src[i];
}

// ---------------- W1 transpose + bf16 convert: [512][128] -> [128][512] ------

__global__ __launch_bounds__(256) void k_w1t(const float* __restrict__ W1,
                                             unsigned short* __restrict__ W1t) {
    int idx = blockIdx.x * 256 + threadIdx.x;    // 65536
    int n = idx >> 9, k = idx & 511;
    W1t[idx] = f2bf(W1[k * HID + n]);
}

// ------- GEMM1 (MFMA bf16): h1s = (x @ W1) * inv[row], stored bf16 ----------
// 128x128 block tile, 4 waves, each 64x64 (4x4 of 16x16x32 MFMA), BK=32.
// A-tile fp32->bf16 staging uses v_cvt_pk_bf16_f32 (packed) — 1 instr / 2 elems.

#define GM 128

__global__ __launch_bounds__(256) void k_gemm1_mfma(
    const float* __restrict__ A,            // x [M,512] fp32
    const unsigned short* __restrict__ Bt,  // W1t [128,512] bf16
    const float* __restrict__ inv,
    unsigned short* __restrict__ C,         // h1s [M,128] bf16
    int M)
{
    __shared__ unsigned short Asl[128 * 40];   // 10240 B
    __shared__ unsigned short Bsl[128 * 40];   // 10240 B

    const int tid  = threadIdx.x;
    const int wave = tid >> 6;
    const int lane = tid & 63;
    const int quad = lane >> 4;
    const int l15  = lane & 15;
    const int wm   = (wave >> 1) * 64;
    const int wn   = (wave & 1) * 64;
    const int block_m = blockIdx.x * GM;

    floatx4 acc[4][4];
    #pragma unroll
    for (int i = 0; i < 4; ++i)
        #pragma unroll
        for (int j = 0; j < 4; ++j) acc[i][j] = (floatx4){0.f, 0.f, 0.f, 0.f};

    for (int k0 = 0; k0 < F_IN; k0 += 32) {
        #pragma unroll
        for (int i = 0; i < 4; ++i) {
            int f  = tid + 256 * i;
            int r  = f >> 3;
            int kq = f & 7;
            int gr = block_m + r;
            gr = gr < M ? gr : M - 1;   // clamp (rows >= M never stored)
            floatx4 v = *(const floatx4*)&A[(size_t)gr * F_IN + k0 + kq * 4];
            *(uint2*)&Asl[r * 40 + kq * 4] =
                make_uint2(pk2bf(v.x, v.y), pk2bf(v.z, v.w));
        }
        #pragma unroll
        for (int i = 0; i < 2; ++i) {
            int f  = tid + 256 * i;
            int r  = f >> 2;
            int kq = f & 3;
            int4 v = *(const int4*)&Bt[(size_t)r * F_IN + k0 + kq * 8];
            *(int4*)&Bsl[r * 40 + kq * 8] = v;
        }
        __syncthreads();

        short8 af[4], bf[4];
        #pragma unroll
        for (int t = 0; t < 4; ++t)
            af[t] = *(const short8*)&Asl[(wm + t * 16 + l15) * 40 + quad * 8];
        #pragma unroll
        for (int t = 0; t < 4; ++t)
            bf[t] = *(const short8*)&Bsl[(wn + t * 16 + l15) * 40 + quad * 8];

        #pragma unroll
        for (int tm = 0; tm < 4; ++tm)
            #pragma unroll
            for (int tn = 0; tn < 4; ++tn)
                acc[tm][tn] = __builtin_amdgcn_mfma_f32_16x16x32_bf16(
                    af[tm], bf[tn], acc[tm][tn], 0, 0, 0);
        __syncthreads();
    }

    // C/D layout: col = l15, row = quad*4 + reg; fold inv[row], store bf16
    #pragma unroll
    for (int tm = 0; tm < 4; ++tm) {
        #pragma unroll
        for (int r = 0; r < 4; ++r) {
            int row = block_m + wm + tm * 16 + quad * 4 + r;
            if (row < M) {
                float iv = inv[row];
                #pragma unroll
                for (int tn = 0; tn < 4; ++tn)
                    C[(size_t)row * HID + wn + tn * 16 + l15] =
                        f2bf(acc[tm][tn][r] * iv);
            }
        }
    }
}

// ------- gather1: hrelu = relu(invd * (self + sum nbr h1s rows) + b1) -------
// one wave per node; lane = bf16x2 feature pair; 8/4/1-edge unroll for MLP

__global__ __launch_bounds__(256) void k_gather1(
    const unsigned* __restrict__ h1s,   // [N][64] uints (bf16x2)
    const int* __restrict__ rp, const int* __restrict__ deg,
    const float* __restrict__ inv, const int* __restrict__ csr_src,
    const float* __restrict__ b1, float* __restrict__ hrelu)
{
    const int wave = threadIdx.x >> 6;
    const int lane = threadIdx.x & 63;
    const int node = blockIdx.x * 4 + wave;   // N divisible by 4
    const int start = rp[node];
    const int cnt = deg[node];

    unsigned u = h1s[(size_t)node * 64 + lane];   // self row
    float acc0 = bflo(u), acc1 = bfhi(u);

    int t = 0;
    for (; t + 8 <= cnt; t += 8) {
        int s0 = csr_src[start + t + 0];
        int s1 = csr_src[start + t + 1];
        int s2 = csr_src[start + t + 2];
        int s3 = csr_src[start + t + 3];
        int s4 = csr_src[start + t + 4];
        int s5 = csr_src[start + t + 5];
        int s6 = csr_src[start + t + 6];
        int s7 = csr_src[start + t + 7];
        unsigned u0 = h1s[(size_t)s0 * 64 + lane];
        unsigned u1 = h1s[(size_t)s1 * 64 + lane];
        unsigned u2 = h1s[(size_t)s2 * 64 + lane];
        unsigned u3 = h1s[(size_t)s3 * 64 + lane];
        unsigned u4 = h1s[(size_t)s4 * 64 + lane];
        unsigned u5 = h1s[(size_t)s5 * 64 + lane];
        unsigned u6 = h1s[(size_t)s6 * 64 + lane];
        unsigned u7 = h1s[(size_t)s7 * 64 + lane];
        acc0 += ((bflo(u0) + bflo(u1)) + (bflo(u2) + bflo(u3)))
              + ((bflo(u4) + bflo(u5)) + (bflo(u6) + bflo(u7)));
        acc1 += ((bfhi(u0) + bfhi(u1)) + (bfhi(u2) + bfhi(u3)))
              + ((bfhi(u4) + bfhi(u5)) + (bfhi(u6) + bfhi(u7)));
    }
    for (; t + 4 <= cnt; t += 4) {
        int s0 = csr_src[start + t + 0];
        int s1 = csr_src[start + t + 1];
        int s2 = csr_src[start + t + 2];
        int s3 = csr_src[start + t + 3];
        unsigned u0 = h1s[(size_t)s0 * 64 + lane];
        unsigned u1 = h1s[(size_t)s1 * 64 + lane];
        unsigned u2 = h1s[(size_t)s2 * 64 + lane];
        unsigned u3 = h1s[(size_t)s3 * 64 + lane];
        acc0 += (bflo(u0) + bflo(u1)) + (bflo(u2) + bflo(u3));
        acc1 += (bfhi(u0) + bfhi(u1)) + (bfhi(u2) + bfhi(u3));
    }
    for (; t < cnt; ++t) {
        int s = csr_src[start + t];
        unsigned uu = h1s[(size_t)s * 64 + lane];
        acc0 += bflo(uu);
        acc1 += bfhi(uu);
    }

    float invd = inv[node];
    float2 b = *(const float2*)&b1[lane * 2];
    float v0 = fmaxf(acc0 * invd + b.x, 0.f);
    float v1 = fmaxf(acc1 * invd + b.y, 0.f);
    *(float2*)&hrelu[(size_t)node * HID + lane * 2] = make_float2(v0, v1);
}

// ------- GEMM2: h2s = (hrelu @ W2) * inv[node], stored bf16 ----------------

__global__ __launch_bounds__(256) void k_gemm2(
    const float* __restrict__ H, const float* __restrict__ W,
    const float* __restrict__ inv, unsigned short* __restrict__ h2s)
{
    __shared__ float Ws[HID * NCLS];
    for (int i = threadIdx.x; i < HID * NCLS; i += 256) Ws[i] = W[i];
    __syncthreads();
    int idx = blockIdx.x * 256 + threadIdx.x;   // grid exact: N*40
    unsigned node = (unsigned)idx / NCLS;
    unsigned j = (unsigned)idx - node * NCLS;
    const float* hrow = H + (size_t)node * HID;
    float acc = 0.f;
    #pragma unroll 8
    for (int k = 0; k < HID; ++k) acc += hrow[k] * Ws[k * NCLS + j];
    h2s[idx] = f2bf(acc * inv[node]);
}

// ------- gather2: fused aggregation + bias + log_softmax -------------------
// one wave per node; lanes = 3 edge-groups x 20 bf16x2 feature pairs

__global__ __launch_bounds__(256) void k_gather2(
    const unsigned* __restrict__ h2s,   // [N][20] uints (bf16x2)
    const int* __restrict__ rp, const int* __restrict__ deg,
    const float* __restrict__ inv, const int* __restrict__ csr_src,
    const float* __restrict__ b2, float* __restrict__ out)
{
    const int wave = threadIdx.x >> 6;
    const int lane = threadIdx.x & 63;
    const int node = blockIdx.x * 4 + wave;   // N divisible by 4
    const int g = lane / 20;                  // 0,1,2 active; 3 idle
    const int j = lane - g * 20;              // feature pair 0..19
    const int start = rp[node];
    const int cnt = deg[node];

    float acc0 = 0.f, acc1 = 0.f;
    if (g == 0) {                             // self row
        unsigned u = h2s[(size_t)node * 20 + j];
        acc0 = bflo(u);
        acc1 = bfhi(u);
    }
    if (g < 3) {
        int t = g;
        for (; t + 3 < cnt; t += 6) {         // 2 edges per iter per group
            int s0 = csr_src[start + t];
            int s1 = csr_src[start + t + 3];
            unsigned u0 = h2s[(size_t)s0 * 20 + j];
            unsigned u1 = h2s[(size_t)s1 * 20 + j];
            acc0 += bflo(u0) + bflo(u1);
            acc1 += bfhi(u0) + bfhi(u1);
        }
        if (t < cnt) {
            int s = csr_src[start + t];
            unsigned u = h2s[(size_t)s * 20 + j];
            acc0 += bflo(u);
            acc1 += bfhi(u);
        }
    }
    // fold edge-groups 1,2 into group 0
    acc0 += __shfl(acc0, j + 20) + __shfl(acc0, j + 40);
    acc1 += __shfl(acc1, j + 20) + __shfl(acc1, j + 40);

    float invd = inv[node];
    float v0 = -INFINITY, v1 = -INFINITY;
    if (g == 0) {
        float2 b = *(const float2*)&b2[j * 2];
        v0 = acc0 * invd + b.x;
        v1 = acc1 * invd + b.y;
    }
    float m = fmaxf(v0, v1);
    #pragma unroll
    for (int mask = 16; mask; mask >>= 1) m = fmaxf(m, __shfl_xor(m, mask));
    float e = (g == 0) ? (__expf(v0 - m) + __expf(v1 - m)) : 0.f;
    #pragma unroll
    for (int mask = 16; mask; mask >>= 1) e += __shfl_xor(e, mask);
    if (g == 0) {
        float lg = __logf(e);
        *(float2*)&out[(size_t)node * NCLS + j * 2] =
            make_float2(v0 - m - lg, v1 - m - lg);
    }
}

// ---------------- launch ----------------

extern "C" void kernel_launch(void* const* d_in, const int* in_sizes, int n_in,
                              void* d_out, int out_size, void* d_ws, size_t ws_size,
                              hipStream_t stream) {
    const float* x   = (const float*)d_in[0];
    const int*   ei  = (const int*)d_in[1];
    const float* W1  = (const float*)d_in[2];
    const float* b1  = (const float*)d_in[3];
    const float* W2  = (const float*)d_in[4];
    const float* b2  = (const float*)d_in[5];
    float* out = (float*)d_out;

    const int* src = ei;
    const int* dst = ei + N_EDGES;

    // workspace layout (4-byte units)
    char* wsb = (char*)d_ws;
    float* inv      = (float*)wsb;                                  // 131072
    float* slot1    = inv + 131072;                                 // 12.8M floats
    float* hrelu    = slot1 + (size_t)N_NODES * HID;                // 12.8M floats
    int*   deg      = (int*)(hrelu + (size_t)N_NODES * HID);        // 131072
    int*   rp       = deg + 131072;                                 // 131072
    int*   cursor   = rp + 131072;                                  // 131072 (dead after k_fill)
    int*   bsums    = cursor + 131072;                              // 1024
    int*   csr_src  = bsums + 1024;                                 // 1.6M
    unsigned short* h1s_st = (unsigned short*)slot1;                // N*128 bf16 (store view)
    unsigned short* h2s_st = (unsigned short*)slot1;                // N*40 bf16 (store view)
    unsigned* h1s_ld = (unsigned*)slot1;                            // packed bf16x2 load view
    unsigned* h2s_ld = (unsigned*)slot1;                            // packed bf16x2 load view
    unsigned short* W1t = (unsigned short*)cursor;                  // reuse after k_fill

    const int T = 256;
    const int NB = (N_NODES + SCAN_B - 1) / SCAN_B;   // 391

    // degree
    k_zero_int<<<131072 / T, T, 0, stream>>>(deg, 131072);
    k_count_deg<<<N_EDGES / T, T, 0, stream>>>(dst, deg, N_EDGES);

    // CSR build (+inv fused into scan1, cursor init fused into scan3)
    k_scan1<<<NB, SCAN_B, 0, stream>>>(deg, rp, bsums, inv, N_NODES);
    k_scan2<<<1, 512, 0, stream>>>(bsums, NB);
    k_scan3<<<NB, SCAN_B, 0, stream>>>(rp, bsums, cursor, N_NODES);
    k_fill<<<N_EDGES / T, T, 0, stream>>>(src, dst, cursor, csr_src, N_EDGES);

    // W1 -> bf16 transposed (after k_fill: W1t reuses cursor's storage)
    k_w1t<<<(F_IN * HID) / T, T, 0, stream>>>(W1, W1t);

    // layer 1
    k_gemm1_mfma<<<(N_NODES + GM - 1) / GM, T, 0, stream>>>(x, W1t, inv, h1s_st, N_NODES);
    k_gather1<<<N_NODES / 4, T, 0, stream>>>(h1s_ld, rp, deg, inv, csr_src, b1, hrelu);

    // layer 2 (h2s aliases h1s — dead after gather1)
    k_gemm2<<<(N_NODES * NCLS) / T, T, 0, stream>>>(hrelu, W2, inv, h2s_st);
    k_gather2<<<N_NODES / 4, T, 0, stream>>>(h2s_ld, rp, deg, inv, csr_src, b2, out);
}